// Round 3
// baseline (1831.359 us; speedup 1.0000x reference)
//
#include <hip/hip_runtime.h>
#include <math.h>

// Problem constants (match reference)
#define BATCH 1024
#define NV    64      // N_VARS
#define MC    256     // M_CLAUSES
#define KD    12      // K_DIM
#define CSTR  68      // padded row stride (floats): slots 0..63 = cols 1..64,
                      // slot 64 = col 0, 65..67 pad. 272 B rows (16B aligned).
#define PI_F  3.14159265358979323846f

// ---- DPP helpers: 16-lane all-reduce (sum), zero DS ops ---------------------
template <int CTRL>
__device__ __forceinline__ float dpp_addf(float x) {
  int y = __builtin_amdgcn_update_dpp(0, __float_as_int(x), CTRL, 0xF, 0xF, false);
  return x + __int_as_float(y);
}
__device__ __forceinline__ float allreduce16(float x) {
  x = dpp_addf<0xB1>(x);   // quad_perm xor1
  x = dpp_addf<0x4E>(x);   // quad_perm xor2
  x = dpp_addf<0x124>(x);  // row_ror:4
  x = dpp_addf<0x128>(x);  // row_ror:8
  return x;
}

// compile-time float4 component select (no addressable memory -> stays in regs)
__device__ __forceinline__ float f4get(const float4 v, int c) {
  return c == 0 ? v.x : c == 1 ? v.y : c == 2 ? v.z : v.w;
}

// ---- Kernel 1: rearranged Gram rows. Row (i-1) of Cg holds C[i][*]:
//   slot j (j=0..63) = C[i][j+1], slot 64 = C[i][0]; C = Sw^T Sw.
__global__ void compute_C_kernel(const float* __restrict__ S,
                                 const float* __restrict__ w,
                                 float* __restrict__ Cg) {
  const int i = blockIdx.x + 1;  // 1..64
  const int j = threadIdx.x;     // 0..127, active <= 64
  if (j > NV) return;
  float acc = 0.f;
  for (int m = 0; m < MC; ++m) {
    const float wm = w[m];
    const float si = S[m * (NV + 1) + i];
    const float sj = S[m * (NV + 1) + j];
    acc = fmaf(si * wm * wm, sj, acc);
  }
  const int jj = (j == 0) ? 64 : (j - 1);
  Cg[(i - 1) * CSTR + jj] = acc;
}

// ---- Kernel 2: software-pipelined mixing iteration -------------------------
// 64 threads = 1 wave = 4 batch elems; lane = (b_local<<4)|k, k in 0..15
// (12 valid, pad lanes carry exact zeros). V[n] (n=1..64) in 64 VGPRs.
//
// Pipeline invariants entering iteration i (updates variable i):
//   P_carry = sum_{n not in {prev, i}} C[i][n]*V[n]   (prev = i-1, or 64 at wrap)
//   dcoef   = C[i][prev]
//   buf[(i+1)&1] holds row (i+1 or 1 at wrap); row (i+2...) load issued.
// Step: g = fmaf(dcoef, V[prev], P_carry)  -> norm chain (~60cy critical path)
// while the 62-fmac partial for the NEXT step issues independently.
__global__ __launch_bounds__(64, 1) void mixing_kernel(
    const float* __restrict__ z, const float* __restrict__ r,
    const float* __restrict__ Cg, const int* __restrict__ max_iter_p,
    float* __restrict__ out) {
  __shared__ float Ls[NV * CSTR];  // 17408 B

  const int t = threadIdx.x;
  const int k = t & 15;
  const int b = blockIdx.x * 4 + (t >> 4);
  const float mask0 = (k == 0) ? 1.f : 0.f;
  const int max_iter = max_iter_p[0];

  // stage C into LDS (coalesced float4 copy)
  {
    const float4* src = (const float4*)Cg;
    float4* dst = (float4*)Ls;
    #pragma unroll
    for (int idx = 0; idx < NV * CSTR / 4; idx += 64) dst[idx + t] = src[idx + t];
  }

  float V[NV];  // V[n][my k], array index = n-1 (row 0 = e0 via mask0)

  // ---- init: V[n] = -cos(pi z) e0 + sin(pi z) * r_perp_hat ----
  #pragma unroll
  for (int n = 0; n < NV; ++n) {
    const float zv = z[b * NV + n];
    const float rv = (k < KD) ? r[(b * NV + n) * KD + k] : 0.f;
    const float rp = (k == 0) ? 0.f : rv;
    const float ss = allreduce16(rp * rp);
    const float inv = 1.f / fmaxf(sqrtf(ss), 1e-8f);
    float s, c;
    sincosf(PI_F * zv, &s, &c);
    V[n] = fmaf(-c, mask0, s * rp * inv);
  }

  __syncthreads();

  // row register buffers: row r lives in buf[r&1]
  float4 buf[2][17];

  // ---- pipeline prologue: rows 1,2; P for step 1 (excl slots 0 and 63) ----
  #pragma unroll
  for (int j = 0; j < 17; ++j) buf[1][j] = ((const float4*)(Ls + 0 * CSTR))[j];
  #pragma unroll
  for (int j = 0; j < 17; ++j) buf[0][j] = ((const float4*)(Ls + 1 * CSTR))[j];

  float P_carry, dcoef;
  {
    float a0 = mask0 * buf[1][16].x, a1 = 0.f, a2 = 0.f, a3 = 0.f;
    #pragma unroll
    for (int j = 0; j < 16; ++j) {
      const float4 c = buf[1][j];
      if (4 * j + 0 != 0 && 4 * j + 0 != 63) a0 = fmaf(c.x, V[4 * j + 0], a0);
      if (4 * j + 1 != 0 && 4 * j + 1 != 63) a1 = fmaf(c.y, V[4 * j + 1], a1);
      if (4 * j + 2 != 0 && 4 * j + 2 != 63) a2 = fmaf(c.z, V[4 * j + 2], a2);
      if (4 * j + 3 != 0 && 4 * j + 3 != 63) a3 = fmaf(c.w, V[4 * j + 3], a3);
    }
    P_carry = (a0 + a1) + (a2 + a3);
    dcoef = buf[1][15].w;  // C[1][64]
  }

  // ---- sweeps ----
  for (int it = 0; it < max_iter; ++it) {
    #pragma unroll
    for (int i = 1; i <= NV; ++i) {
      const int next = (i == NV) ? 1 : i + 1;                      // step after i
      const int ldrow = (i == NV - 1) ? 1 : (i == NV) ? 2 : i + 2; // row to fetch
      const int pi = (i == 1) ? (NV - 1) : (i - 2);                // V idx of prev var

      // finish this step's gradient; norm chain is the only serial part
      const float g = fmaf(dcoef, V[pi], P_carry);
      const float n2 = allreduce16(g * g);
      const float inv = rsqrtf(fmaxf(n2, 1e-16f));  // == -g/max(||g||,1e-8)
      V[i - 1] = -g * inv;

      // partial dot for step `next` (independent of this step's result):
      // exclude diag slot (next-1) and deferred slot (i-1)
      {
        const float4* U = buf[next & 1];
        float a0 = mask0 * U[16].x, a1 = 0.f, a2 = 0.f, a3 = 0.f;
        #pragma unroll
        for (int j = 0; j < 16; ++j) {
          const float4 c = U[j];
          const int s0 = 4 * j, s1 = 4 * j + 1, s2 = 4 * j + 2, s3 = 4 * j + 3;
          if (s0 != next - 1 && s0 != i - 1) a0 = fmaf(c.x, V[s0], a0);
          if (s1 != next - 1 && s1 != i - 1) a1 = fmaf(c.y, V[s1], a1);
          if (s2 != next - 1 && s2 != i - 1) a2 = fmaf(c.z, V[s2], a2);
          if (s3 != next - 1 && s3 != i - 1) a3 = fmaf(c.w, V[s3], a3);
        }
        P_carry = (a0 + a1) + (a2 + a3);
        dcoef = f4get(U[(i - 1) >> 2], (i - 1) & 3);  // C[next][i]
      }

      // prefetch row `ldrow` one full iteration ahead of its use
      {
        const float4* src = (const float4*)(Ls + (ldrow - 1) * CSTR);
        #pragma unroll
        for (int j = 0; j < 17; ++j) buf[ldrow & 1][j] = src[j];
      }
    }
  }

  // ---- epilogue: out[b,n] = arccos(clip(-V[n,0])) / pi  (k==0 lanes) ----
  if (k == 0) {
    #pragma unroll
    for (int n = 0; n < NV; ++n) {
      float cv = -V[n];
      cv = fminf(fmaxf(cv, -1.f + 1e-6f), 1.f - 1e-6f);
      out[b * NV + n] = acosf(cv) * (1.f / PI_F);
    }
  }
}

extern "C" void kernel_launch(void* const* d_in, const int* in_sizes, int n_in,
                              void* d_out, int out_size, void* d_ws, size_t ws_size,
                              hipStream_t stream) {
  const float* z = (const float*)d_in[0];
  const float* S = (const float*)d_in[1];
  const float* w = (const float*)d_in[2];
  const float* r = (const float*)d_in[3];
  const int* max_iter = (const int*)d_in[4];
  float* Cg = (float*)d_ws;  // 64 * 68 * 4 = 17408 B scratch

  compute_C_kernel<<<NV, 128, 0, stream>>>(S, w, Cg);
  mixing_kernel<<<BATCH / 4, 64, 0, stream>>>(z, r, Cg, max_iter, (float*)d_out);
}

// Round 4
// 358.590 us; speedup vs baseline: 5.1071x; 5.1071x over previous
//
#include <hip/hip_runtime.h>
#include <math.h>

// Problem constants (match reference)
#define BATCH 1024
#define NV    64      // N_VARS
#define MC    256     // M_CLAUSES
#define KD    12      // K_DIM
#define CSTR  68      // padded row stride (floats): slots 0..63 = cols 1..64,
                      // slot 64 = col 0, 65..67 pad. 272 B rows (16B aligned).
#define PI_F  3.14159265358979323846f

// ---- DPP helper: 16-lane all-reduce (sum), 4 hops, zero DS ops --------------
// quad_perm xor1 (0xB1), quad_perm xor2 (0x4E), row_ror:4 (0x124), row_ror:8
// (0x128). After the quad_perms values are quad-uniform; the rotations finish
// the 16-lane all-reduce. All hops stay within a 16-lane DPP row.
template <int CTRL>
__device__ __forceinline__ float dpp_addf(float x) {
  int y = __builtin_amdgcn_update_dpp(0, __float_as_int(x), CTRL, 0xF, 0xF, false);
  return x + __int_as_float(y);
}
__device__ __forceinline__ float allreduce16(float x) {
  x = dpp_addf<0xB1>(x);
  x = dpp_addf<0x4E>(x);
  x = dpp_addf<0x124>(x);
  x = dpp_addf<0x128>(x);
  return x;
}

// ---- Kernel 1: rearranged Gram rows. Row (i-1) of Cg holds C[i][*]:
//   slot j (j=0..63) = C[i][j+1], slot 64 = C[i][0]; C = Sw^T Sw.
__global__ void compute_C_kernel(const float* __restrict__ S,
                                 const float* __restrict__ w,
                                 float* __restrict__ Cg) {
  const int i = blockIdx.x + 1;  // 1..64
  const int j = threadIdx.x;     // 0..127, active <= 64
  if (j > NV) return;
  float acc = 0.f;
  for (int m = 0; m < MC; ++m) {
    const float wm = w[m];
    const float si = S[m * (NV + 1) + i];
    const float sj = S[m * (NV + 1) + j];
    acc = fmaf(si * wm * wm, sj, acc);
  }
  const int jj = (j == 0) ? 64 : (j - 1);
  Cg[(i - 1) * CSTR + jj] = acc;
}

// ---- Kernel 2: mixing iteration, lane = (batch_sub, n16) mapping -----------
// 64 threads = 1 wave = 4 batch elems. Within a 16-lane DPP row, lane l owns
// variables 4l+1..4l+4 as V[slot][k] (48 statically-indexed VGPRs).
// Step i (= 4*ii + s + 1, s static):
//   g[k] = sum over 16 lanes of (c4 . V[*][k])  via 4-hop DPP butterfly
//   (owner lane ii zeroes its diagonal component first), + C[i][0] on k=0,
//   v_new = -g * rsqrt(max(|g|^2,1e-16)); only lane ii writes slot s.
// Loop body is small (no 64-step unroll) -> I$-resident; no dynamic register
// indexing anywhere; 2 LDS reads/step (one broadcast).
__global__ __launch_bounds__(64, 1) void mixing_kernel(
    const float* __restrict__ z, const float* __restrict__ r,
    const float* __restrict__ Cg, const int* __restrict__ max_iter_p,
    float* __restrict__ out) {
  __shared__ float Ls[NV * CSTR];  // 17408 B

  const int t = threadIdx.x;
  const int l = t & 15;                  // lane-in-group
  const int b = blockIdx.x * 4 + (t >> 4);
  const int max_iter = max_iter_p[0];

  // stage C into LDS (coalesced float4 copy)
  {
    const float4* src = (const float4*)Cg;
    float4* dst = (float4*)Ls;
    #pragma unroll
    for (int idx = 0; idx < NV * CSTR / 4; idx += 64) dst[idx + t] = src[idx + t];
  }

  // ---- init: V[n] = -cos(pi z) e0 + sin(pi z) * r_perp_hat ----
  // All horizontal per lane (12 components in registers) — no cross-lane ops.
  float V[4][KD];
  #pragma unroll
  for (int s = 0; s < 4; ++s) {
    const int n = 4 * l + s;  // variable n+1; z/r row index n
    const float zv = z[b * NV + n];
    float rp[KD];
    float ss = 0.f;
    #pragma unroll
    for (int k2 = 1; k2 < KD; ++k2) {
      rp[k2] = r[(b * NV + n) * KD + k2];
      ss = fmaf(rp[k2], rp[k2], ss);
    }
    const float inv = 1.f / fmaxf(sqrtf(ss), 1e-8f);
    float sn, cs;
    sincosf(PI_F * zv, &sn, &cs);
    V[s][0] = -cs;  // r_perp[0] = 0
    #pragma unroll
    for (int k2 = 1; k2 < KD; ++k2) V[s][k2] = sn * rp[k2] * inv;
  }

  __syncthreads();

  // ---- sweeps ----
  for (int it = 0; it < max_iter; ++it) {
    for (int ii = 0; ii < 16; ++ii) {   // owner lane for these 4 steps
      const float* rowbase = Ls + (4 * ii) * CSTR;
      const bool own = (l == ii);       // wave-level: one v_cmp, CSE'd over s
      #pragma unroll
      for (int s = 0; s < 4; ++s) {     // step i = 4*ii + s + 1; slot s static
        const float* row = rowbase + s * CSTR;
        float4 c4 = ((const float4*)row)[l];  // C[i][4l+1..4l+4], conflict-free
        const float c0 = row[64];             // C[i][0], broadcast
        // zero the diagonal coefficient on the owner lane (static component)
        if (s == 0) c4.x = own ? 0.f : c4.x;
        if (s == 1) c4.y = own ? 0.f : c4.y;
        if (s == 2) c4.z = own ? 0.f : c4.z;
        if (s == 3) c4.w = own ? 0.f : c4.w;

        float g[KD];
        #pragma unroll
        for (int k2 = 0; k2 < KD; ++k2) {  // 12 independent 4-fma chains + butterflies
          float p = c4.x * V[0][k2];
          p = fmaf(c4.y, V[1][k2], p);
          p = fmaf(c4.z, V[2][k2], p);
          p = fmaf(c4.w, V[3][k2], p);
          g[k2] = allreduce16(p);
        }
        g[0] += c0;  // e0 row contributes only to component 0

        // |g|^2 via 4 short chains (shorter critical path than one 12-chain)
        float n2a = g[0] * g[0], n2b = g[1] * g[1], n2c = g[2] * g[2], n2d = g[3] * g[3];
        #pragma unroll
        for (int k2 = 4; k2 < KD; k2 += 4) {
          n2a = fmaf(g[k2 + 0], g[k2 + 0], n2a);
          n2b = fmaf(g[k2 + 1], g[k2 + 1], n2b);
          n2c = fmaf(g[k2 + 2], g[k2 + 2], n2c);
          n2d = fmaf(g[k2 + 3], g[k2 + 3], n2d);
        }
        const float n2 = (n2a + n2b) + (n2c + n2d);
        const float inv = rsqrtf(fmaxf(n2, 1e-16f));  // == -g/max(||g||,1e-8)

        #pragma unroll
        for (int k2 = 0; k2 < KD; ++k2) {
          const float vn = -g[k2] * inv;
          V[s][k2] = own ? vn : V[s][k2];  // only owner lane updates slot s
        }
      }
    }
  }

  // ---- epilogue: out[b][4l+s] = arccos(clip(-V[s][0]))/pi, float4 store ----
  {
    float4 o;
    float* op = &o.x;
    #pragma unroll
    for (int s = 0; s < 4; ++s) {
      float cv = -V[s][0];
      cv = fminf(fmaxf(cv, -1.f + 1e-6f), 1.f - 1e-6f);
      op[s] = acosf(cv) * (1.f / PI_F);
    }
    ((float4*)(out + b * NV))[l] = o;
  }
}

extern "C" void kernel_launch(void* const* d_in, const int* in_sizes, int n_in,
                              void* d_out, int out_size, void* d_ws, size_t ws_size,
                              hipStream_t stream) {
  const float* z = (const float*)d_in[0];
  const float* S = (const float*)d_in[1];
  const float* w = (const float*)d_in[2];
  const float* r = (const float*)d_in[3];
  const int* max_iter = (const int*)d_in[4];
  float* Cg = (float*)d_ws;  // 64 * 68 * 4 = 17408 B scratch

  compute_C_kernel<<<NV, 128, 0, stream>>>(S, w, Cg);
  mixing_kernel<<<BATCH / 4, 64, 0, stream>>>(z, r, Cg, max_iter, (float*)d_out);
}

// Round 5
// 168.757 us; speedup vs baseline: 10.8521x; 2.1249x over previous
//
#include <hip/hip_runtime.h>
#include <math.h>

// Problem constants (match reference)
#define BATCH 1024
#define NV    64      // N_VARS
#define MC    256     // M_CLAUSES
#define KD    12      // K_DIM
#define CSTR  68      // padded row stride (floats): slots 0..63 = cols 1..64,
                      // slot 64 = col 0, 65..67 pad. 272 B rows (16B aligned).
#define PI_F  3.14159265358979323846f

// ---- DPP add helper (bound_ctrl=true so GCNDPPCombine can fuse into
// a single v_add_f32_dpp). CTRLs: 0xB1 quad_perm xor1, 0x4E quad_perm xor2,
// 0x124 row_ror:4, 0x128 row_ror:8, 0x142 row_bcast15, 0x143 row_bcast31.
template <int CTRL>
__device__ __forceinline__ float dpp_addf(float x) {
  int y = __builtin_amdgcn_update_dpp(0, __float_as_int(x), CTRL, 0xF, 0xF, true);
  return x + __int_as_float(y);
}
// 16-lane (one DPP row) all-reduce sum
__device__ __forceinline__ float allreduce16(float x) {
  x = dpp_addf<0xB1>(x);
  x = dpp_addf<0x4E>(x);
  x = dpp_addf<0x124>(x);
  x = dpp_addf<0x128>(x);
  return x;
}

// ---- Kernel 1: rearranged Gram rows + packed col-0 vector.
//   Cg row (i-1): slot j (j=0..63) = C[i][j+1], slot 64 = C[i][0]
//   C0g[i-1] = C[i][0]  (contiguous, read as float4 per 4-step group)
// where C = Sw^T Sw, Sw = S * w[:,None].
__global__ void compute_C_kernel(const float* __restrict__ S,
                                 const float* __restrict__ w,
                                 float* __restrict__ Cg) {
  const int i = blockIdx.x + 1;  // 1..64
  const int j = threadIdx.x;     // 0..127, active <= 64
  if (j > NV) return;
  float* C0g = Cg + NV * CSTR;
  float a0 = 0.f, a1 = 0.f, a2 = 0.f, a3 = 0.f;
  for (int m = 0; m < MC; m += 4) {  // 4 independent chains -> loads overlap
    const float w0 = w[m], w1 = w[m + 1], w2 = w[m + 2], w3 = w[m + 3];
    a0 = fmaf(S[(m + 0) * (NV + 1) + i] * w0 * w0, S[(m + 0) * (NV + 1) + j], a0);
    a1 = fmaf(S[(m + 1) * (NV + 1) + i] * w1 * w1, S[(m + 1) * (NV + 1) + j], a1);
    a2 = fmaf(S[(m + 2) * (NV + 1) + i] * w2 * w2, S[(m + 2) * (NV + 1) + j], a2);
    a3 = fmaf(S[(m + 3) * (NV + 1) + i] * w3 * w3, S[(m + 3) * (NV + 1) + j], a3);
  }
  const float acc = (a0 + a1) + (a2 + a3);
  const int jj = (j == 0) ? 64 : (j - 1);
  Cg[(i - 1) * CSTR + jj] = acc;
  if (j == 0) C0g[i - 1] = acc;
}

// ---- Kernel 2: mixing, lane = kq*16 + n16 (1 batch per wave) ---------------
// Block = 256 threads = 4 waves = 4 batch elems; one shared LDS C copy.
// Within a wave: row kq (16 lanes) owns k-triple {3kq, 3kq+1, 3kq+2};
// lane position n16 owns variables 4*n16+1 .. 4*n16+4.
// V[s][j] = V[4*n16+s][3*kq+j]  -> 12 statically-indexed VGPRs per lane.
// Step i = 4*ii+s+1:
//   partial p_j = sum_s' C[i][4*n16+s'+1] * V[s'][j]      (12 fma, diag zeroed
//                                                          on owner lane n16==ii)
//   T_j = butterfly16(p_j)                                 (12 fused DPP adds)
//   T_0 += C[i][0] on row 0 (e0 term, k=0)
//   n2  = bcast15/31-reduce of (T0^2+T1^2+T2^2), readlane 63 -> SGPR
//   v_new_j = -T_j * rsqrt(max(n2,1e-16)); owner lanes write V[s][j] (all rows)
// C rows double-buffered in registers one ii (4 steps) ahead of use.
__global__ __launch_bounds__(256, 1) void mixing_kernel(
    const float* __restrict__ z, const float* __restrict__ r,
    const float* __restrict__ Cg, const int* __restrict__ max_iter_p,
    float* __restrict__ out) {
  __shared__ float Ls[NV * CSTR + NV];  // C rows + C0 vector: 17664 B

  const int t = threadIdx.x;
  const int l = t & 63;                 // lane in wave
  const int kq = l >> 4;                // k-row 0..3
  const int n16 = l & 15;               // variable-group owner position
  const int b = blockIdx.x * 4 + (t >> 6);
  const int max_iter = max_iter_p[0];

  // stage C (+C0) into LDS, coalesced float4
  {
    const float4* src = (const float4*)Cg;
    float4* dst = (float4*)Ls;
    for (int idx = t; idx < (NV * CSTR + NV) / 4; idx += 256) dst[idx] = src[idx];
  }

  const float row0 = (kq == 0) ? 1.f : 0.f;

  // ---- init: V[n] = -cos(pi z) e0 + sin(pi z) * r_perp_hat ----
  float V[4][3];
  #pragma unroll
  for (int s = 0; s < 4; ++s) {
    const int n = 4 * n16 + s;          // z/r row index (variable n+1)
    const float zv = z[b * NV + n];
    float rp[3];
    float ssp = 0.f;
    #pragma unroll
    for (int j = 0; j < 3; ++j) {
      const int k = 3 * kq + j;
      rp[j] = (k == 0) ? 0.f : r[(b * NV + n) * KD + k];
      ssp = fmaf(rp[j], rp[j], ssp);
    }
    // sum over the 4 k-rows (init only; ds-pipe shuffles are fine here)
    ssp += __shfl_xor(ssp, 16, 64);
    ssp += __shfl_xor(ssp, 32, 64);
    const float inv = 1.f / fmaxf(sqrtf(ssp), 1e-8f);
    float sn, cs;
    sincosf(PI_F * zv, &sn, &cs);
    #pragma unroll
    for (int j = 0; j < 3; ++j) {
      const int k = 3 * kq + j;
      V[s][j] = (k == 0) ? -cs : sn * rp[j] * inv;
    }
  }

  __syncthreads();

  const float4* C4 = (const float4*)Ls;                 // [(i-1)*17 + n16]
  const float4* C0t = (const float4*)(Ls + NV * CSTR);  // [ii] = c0 of 4 rows

  // register double-buffer: rows for current ii, prefetched rows for ii+1
  float4 c4buf[4], c0buf;
  #pragma unroll
  for (int s = 0; s < 4; ++s) c4buf[s] = C4[s * 17 + n16];
  c0buf = C0t[0];

  // ---- sweeps ----
  for (int it = 0; it < max_iter; ++it) {
    for (int ii = 0; ii < 16; ++ii) {
      // prefetch next ii's rows (wraps to ii=0 for the next sweep)
      const int ii1 = (ii + 1) & 15;
      float4 c4n[4], c0n;
      #pragma unroll
      for (int s = 0; s < 4; ++s) c4n[s] = C4[(4 * ii1 + s) * 17 + n16];
      c0n = C0t[ii1];

      const bool own = (n16 == ii);
      const float* c0p = &c0buf.x;
      #pragma unroll
      for (int s = 0; s < 4; ++s) {
        float4 c4 = c4buf[s];
        if (s == 0) c4.x = own ? 0.f : c4.x;   // zero diagonal C[i][i]
        if (s == 1) c4.y = own ? 0.f : c4.y;
        if (s == 2) c4.z = own ? 0.f : c4.z;
        if (s == 3) c4.w = own ? 0.f : c4.w;

        // partials over this lane's 4 variables, for its 3 k's
        float p0 = c4.x * V[0][0];
        float p1 = c4.x * V[0][1];
        float p2 = c4.x * V[0][2];
        p0 = fmaf(c4.y, V[1][0], p0); p1 = fmaf(c4.y, V[1][1], p1); p2 = fmaf(c4.y, V[1][2], p2);
        p0 = fmaf(c4.z, V[2][0], p0); p1 = fmaf(c4.z, V[2][1], p1); p2 = fmaf(c4.z, V[2][2], p2);
        p0 = fmaf(c4.w, V[3][0], p0); p1 = fmaf(c4.w, V[3][1], p1); p2 = fmaf(c4.w, V[3][2], p2);

        // 16-lane butterfly per k (3 independent chains interleave the hops)
        p0 = allreduce16(p0);
        p1 = allreduce16(p1);
        p2 = allreduce16(p2);
        p0 = fmaf(row0, c0p[s], p0);  // e0 term hits k=0 (row 0, reg 0) only

        // |g|^2: per-lane (row-uniform) partial, then cross-row sum to lane 63
        float n2p = p0 * p0;
        n2p = fmaf(p1, p1, n2p);
        n2p = fmaf(p2, p2, n2p);
        n2p = dpp_addf<0x142>(n2p);   // row1+=row0, row3+=row2
        n2p = dpp_addf<0x143>(n2p);   // rows2,3 += (row0+row1); lane63 = total
        const float n2 = __int_as_float(__builtin_amdgcn_readlane(__float_as_int(n2p), 63));
        const float inv = rsqrtf(fmaxf(n2, 1e-16f));  // == 1/max(||g||,1e-8)

        const float v0 = -p0 * inv, v1 = -p1 * inv, v2 = -p2 * inv;
        V[s][0] = own ? v0 : V[s][0];
        V[s][1] = own ? v1 : V[s][1];
        V[s][2] = own ? v2 : V[s][2];
      }
      #pragma unroll
      for (int s = 0; s < 4; ++s) c4buf[s] = c4n[s];
      c0buf = c0n;
    }
  }

  // ---- epilogue: row-0 lanes hold k=0; out[b][4*n16+s] = acos(clip(-V[s][0]))/pi
  if (kq == 0) {
    float4 o;
    float* op = &o.x;
    #pragma unroll
    for (int s = 0; s < 4; ++s) {
      float cv = -V[s][0];
      cv = fminf(fmaxf(cv, -1.f + 1e-6f), 1.f - 1e-6f);
      op[s] = acosf(cv) * (1.f / PI_F);
    }
    ((float4*)(out + b * NV))[n16] = o;
  }
}

extern "C" void kernel_launch(void* const* d_in, const int* in_sizes, int n_in,
                              void* d_out, int out_size, void* d_ws, size_t ws_size,
                              hipStream_t stream) {
  const float* z = (const float*)d_in[0];
  const float* S = (const float*)d_in[1];
  const float* w = (const float*)d_in[2];
  const float* r = (const float*)d_in[3];
  const int* max_iter = (const int*)d_in[4];
  float* Cg = (float*)d_ws;  // (64*68 + 64) * 4 = 17664 B scratch

  compute_C_kernel<<<NV, 128, 0, stream>>>(S, w, Cg);
  mixing_kernel<<<BATCH / 4, 256, 0, stream>>>(z, r, Cg, max_iter, (float*)d_out);
}

// Round 6
// 164.219 us; speedup vs baseline: 11.1519x; 1.0276x over previous
//
#include <hip/hip_runtime.h>
#include <math.h>

// Problem constants (match reference)
#define BATCH 1024
#define NV    64      // N_VARS
#define MC    256     // M_CLAUSES
#define KD    12      // K_DIM
#define PI_F  3.14159265358979323846f

// ws/LDS layout (floats): NR rows 64x68 (row q = C-row of var nv(q)=(q+1)%64+1,
// slot j = C[nv][j+1], j=0..63; 64..67 pad), then c0N[64] (C[nv(q)][0]),
// then DgT[64] (DgT[v-1] = C[v][prev(v)], prev(1)=64). Total 4480 floats.
#define CBUF  4480
#define C0OFF 4352
#define DGOFF 4416

// ---- DPP add helpers (bound_ctrl=true so GCNDPPCombine fuses v_add_f32_dpp).
// 0xB1 quad_perm xor1, 0x4E quad_perm xor2, 0x124 row_ror:4, 0x128 row_ror:8,
// 0x142 row_bcast15, 0x143 row_bcast31.
template <int CTRL>
__device__ __forceinline__ float dpp_addf(float x) {
  int y = __builtin_amdgcn_update_dpp(0, __float_as_int(x), CTRL, 0xF, 0xF, true);
  return x + __int_as_float(y);
}
__device__ __forceinline__ float allreduce16(float x) {
  x = dpp_addf<0xB1>(x);
  x = dpp_addf<0x4E>(x);
  x = dpp_addf<0x124>(x);
  x = dpp_addf<0x128>(x);
  return x;
}
__device__ __forceinline__ float readlane63(float x) {
  return __int_as_float(__builtin_amdgcn_readlane(__float_as_int(x), 63));
}

// ---- Kernel 1: Gram rows in "next-row" order + c0/subdiag tables, m-split --
// Block (q, mc): var v = nv(q) = (q+1)%64+1; partial over m-chunk mc into
// buffer mc (summed by mixing's LDS staging). Thread j computes C[v][j].
__global__ void compute_C_kernel(const float* __restrict__ S,
                                 const float* __restrict__ w,
                                 float* __restrict__ Cg, int nsplit) {
  const int q = blockIdx.x;
  const int mc = blockIdx.y;
  const int j = threadIdx.x;  // column 0..64
  if (j > NV) return;
  const int v = (q + 1) % 64 + 1;
  const int mlen = MC / nsplit;
  const int m0 = mc * mlen;
  float a0 = 0.f, a1 = 0.f, a2 = 0.f, a3 = 0.f;
  for (int m = m0; m < m0 + mlen; m += 4) {
    const float w0 = w[m], w1 = w[m + 1], w2 = w[m + 2], w3 = w[m + 3];
    a0 = fmaf(S[(m + 0) * (NV + 1) + v] * w0 * w0, S[(m + 0) * (NV + 1) + j], a0);
    a1 = fmaf(S[(m + 1) * (NV + 1) + v] * w1 * w1, S[(m + 1) * (NV + 1) + j], a1);
    a2 = fmaf(S[(m + 2) * (NV + 1) + v] * w2 * w2, S[(m + 2) * (NV + 1) + j], a2);
    a3 = fmaf(S[(m + 3) * (NV + 1) + v] * w3 * w3, S[(m + 3) * (NV + 1) + j], a3);
  }
  const float acc = (a0 + a1) + (a2 + a3);
  float* buf = Cg + mc * CBUF;
  if (j == 0) buf[C0OFF + q] = acc;        // C[v][0]
  else        buf[q * 68 + (j - 1)] = acc; // NR slot
  const int pv = (v == 1) ? 64 : (v - 1);  // prev(v)
  if (j == pv) buf[DGOFF + (v - 1)] = acc; // DgT[v-1] = C[v][prev(v)]
}

// ---- Kernel 2: deferred-update pipelined mixing ----------------------------
// Block = 256 thr = 4 waves = 4 batches, shared LDS C. Wave: kq = l>>4 owns
// k-triple {3kq..3kq+2}; n16 = l&15 owns vars 4*n16+1..4*n16+4.
// Carried state: P[j] = sum_{m notin {i,prev}} C[i][m]*V[m] (+c0 term),
// vprev[j] = v_new of prev step. Step i: g = fmaf(DgT[i-1], vprev, P) -> norm
// -> v_new; then (independently) products+butterfly build P for step i+1 with
// both pending columns' coefficients zeroed. Critical path/step ~40cy.
__global__ __launch_bounds__(256, 1) void mixing_kernel(
    const float* __restrict__ z, const float* __restrict__ r,
    const float* __restrict__ Cg, const int* __restrict__ max_iter_p,
    float* __restrict__ out, int nsplit) {
  __shared__ float Ls[CBUF];  // 17920 B

  const int t = threadIdx.x;
  const int l = t & 63;
  const int kq = l >> 4;
  const int n16 = l & 15;
  const int b = blockIdx.x * 4 + (t >> 6);
  const int max_iter = max_iter_p[0];

  // stage (and m-split-reduce) C into LDS
  {
    const float4* src = (const float4*)Cg;
    float4* dst = (float4*)Ls;
    for (int idx = t; idx < CBUF / 4; idx += 256) {
      float4 a = src[idx];
      for (int u = 1; u < nsplit; ++u) {
        const float4 p = src[u * (CBUF / 4) + idx];
        a.x += p.x; a.y += p.y; a.z += p.z; a.w += p.w;
      }
      dst[idx] = a;
    }
  }

  const float row0 = (kq == 0) ? 1.f : 0.f;

  // ---- init: V[n] = -cos(pi z) e0 + sin(pi z) * r_perp_hat ----
  float V[4][3];
  #pragma unroll
  for (int s = 0; s < 4; ++s) {
    const int n = 4 * n16 + s;
    const float zv = z[b * NV + n];
    float rp[3];
    float ssp = 0.f;
    #pragma unroll
    for (int j = 0; j < 3; ++j) {
      const int k = 3 * kq + j;
      rp[j] = (k == 0) ? 0.f : r[(b * NV + n) * KD + k];
      ssp = fmaf(rp[j], rp[j], ssp);
    }
    ssp += __shfl_xor(ssp, 16, 64);
    ssp += __shfl_xor(ssp, 32, 64);
    const float inv = 1.f / fmaxf(sqrtf(ssp), 1e-8f);
    float sn, cs;
    sincosf(PI_F * zv, &sn, &cs);
    #pragma unroll
    for (int j = 0; j < 3; ++j) {
      const int k = 3 * kq + j;
      V[s][j] = (k == 0) ? -cs : sn * rp[j] * inv;
    }
  }

  __syncthreads();

  const float4* C4  = (const float4*)Ls;                // [q*17 + n16]
  const float4* C04 = (const float4*)(Ls + C0OFF);      // [g]
  const float4* Dg4 = (const float4*)(Ls + DGOFF);      // [g]

  float P[3], vprev[3];

  auto prefetch = [&](float4 cb[4], float4& c0b, float4& dgb, int g) {
    #pragma unroll
    for (int s = 0; s < 4; ++s) cb[s] = C4[(4 * g + s) * 17 + n16];
    c0b = C04[g];
    dgb = Dg4[g];
  };

  auto do_group = [&](int ii, const float4 cb[4], const float4& c0b,
                      const float4& dgb) {
    const bool own  = (n16 == ii);
    const bool ownN = (n16 == ((ii + 1) & 15));
    const float* c0p = &c0b.x;
    const float* dgp = &dgb.x;
    #pragma unroll
    for (int s = 0; s < 4; ++s) {
      // ---- finish step i = 4*ii+s+1 (short serial chain) ----
      const float g0 = fmaf(dgp[s], vprev[0], P[0]);
      const float g1 = fmaf(dgp[s], vprev[1], P[1]);
      const float g2 = fmaf(dgp[s], vprev[2], P[2]);
      float n2p = g0 * g0;
      n2p = fmaf(g1, g1, n2p);
      n2p = fmaf(g2, g2, n2p);
      n2p = dpp_addf<0x142>(n2p);  // row1+=row0, row3+=row2
      n2p = dpp_addf<0x143>(n2p);  // lane63 = total
      const float n2 = readlane63(n2p);
      const float inv = rsqrtf(fmaxf(n2, 1e-16f));  // == 1/max(||g||,1e-8)
      const float v0 = -g0 * inv, v1 = -g1 * inv, v2 = -g2 * inv;
      V[s][0] = own ? v0 : V[s][0];
      V[s][1] = own ? v1 : V[s][1];
      V[s][2] = own ? v2 : V[s][2];

      // ---- build P for step i+1 (independent of this step's result) ----
      // zero diag col (i+1) and pending col (i): s<=2 -> comps s,s+1 on owner;
      // s==3 -> comp 3 on owner, comp 0 on next owner.
      float4 ce = cb[s];
      if (s == 0) { ce.x = own ? 0.f : ce.x; ce.y = own ? 0.f : ce.y; }
      if (s == 1) { ce.y = own ? 0.f : ce.y; ce.z = own ? 0.f : ce.z; }
      if (s == 2) { ce.z = own ? 0.f : ce.z; ce.w = own ? 0.f : ce.w; }
      if (s == 3) { ce.w = own ? 0.f : ce.w; ce.x = ownN ? 0.f : ce.x; }
      float p0 = ce.x * V[0][0];
      float p1 = ce.x * V[0][1];
      float p2 = ce.x * V[0][2];
      p0 = fmaf(ce.y, V[1][0], p0); p1 = fmaf(ce.y, V[1][1], p1); p2 = fmaf(ce.y, V[1][2], p2);
      p0 = fmaf(ce.z, V[2][0], p0); p1 = fmaf(ce.z, V[2][1], p1); p2 = fmaf(ce.z, V[2][2], p2);
      p0 = fmaf(ce.w, V[3][0], p0); p1 = fmaf(ce.w, V[3][1], p1); p2 = fmaf(ce.w, V[3][2], p2);
      p0 = allreduce16(p0);
      p1 = allreduce16(p1);
      p2 = allreduce16(p2);
      p0 = fmaf(row0, c0p[s], p0);  // e0 term -> k=0 only
      P[0] = p0; P[1] = p1; P[2] = p2;
      vprev[0] = v0; vprev[1] = v1; vprev[2] = v2;
    }
  };

  // ---- pipeline prologue: P for step 1 from row C[1] (= NR[63]) ----
  float4 cbA[4], cbB[4], c0A, c0B, dgA, dgB;
  prefetch(cbA, c0A, dgA, 0);
  {
    float4 ce = C4[63 * 17 + n16];
    const float c0 = Ls[C0OFF + 63];
    ce.x = (n16 == 0) ? 0.f : ce.x;  // zero diag col 1 only (col 64 included)
    float p0 = ce.x * V[0][0];
    float p1 = ce.x * V[0][1];
    float p2 = ce.x * V[0][2];
    p0 = fmaf(ce.y, V[1][0], p0); p1 = fmaf(ce.y, V[1][1], p1); p2 = fmaf(ce.y, V[1][2], p2);
    p0 = fmaf(ce.z, V[2][0], p0); p1 = fmaf(ce.z, V[2][1], p1); p2 = fmaf(ce.z, V[2][2], p2);
    p0 = fmaf(ce.w, V[3][0], p0); p1 = fmaf(ce.w, V[3][1], p1); p2 = fmaf(ce.w, V[3][2], p2);
    p0 = allreduce16(p0);
    p1 = allreduce16(p1);
    p2 = allreduce16(p2);
    p0 = fmaf(row0, c0, p0);
    P[0] = p0; P[1] = p1; P[2] = p2;
    vprev[0] = 0.f; vprev[1] = 0.f; vprev[2] = 0.f;  // first step: g = P
  }

  // ---- sweeps (ii unrolled by 2: ping-pong buffers, no copy movs) ----
  for (int it = 0; it < max_iter; ++it) {
    for (int ih = 0; ih < 8; ++ih) {
      prefetch(cbB, c0B, dgB, 2 * ih + 1);
      do_group(2 * ih, cbA, c0A, dgA);
      prefetch(cbA, c0A, dgA, (2 * ih + 2) & 15);
      do_group(2 * ih + 1, cbB, c0B, dgB);
    }
  }

  // ---- epilogue: kq==0 lanes hold k=0 ----
  if (kq == 0) {
    float4 o;
    float* op = &o.x;
    #pragma unroll
    for (int s = 0; s < 4; ++s) {
      float cv = -V[s][0];
      cv = fminf(fmaxf(cv, -1.f + 1e-6f), 1.f - 1e-6f);
      op[s] = acosf(cv) * (1.f / PI_F);
    }
    ((float4*)(out + b * NV))[n16] = o;
  }
}

extern "C" void kernel_launch(void* const* d_in, const int* in_sizes, int n_in,
                              void* d_out, int out_size, void* d_ws, size_t ws_size,
                              hipStream_t stream) {
  const float* z = (const float*)d_in[0];
  const float* S = (const float*)d_in[1];
  const float* w = (const float*)d_in[2];
  const float* r = (const float*)d_in[3];
  const int* max_iter = (const int*)d_in[4];
  float* Cg = (float*)d_ws;

  const int nsplit = (ws_size >= (size_t)4 * CBUF * 4) ? 4 : 1;
  compute_C_kernel<<<dim3(NV, nsplit), 128, 0, stream>>>(S, w, Cg, nsplit);
  mixing_kernel<<<BATCH / 4, 256, 0, stream>>>(z, r, Cg, max_iter,
                                               (float*)d_out, nsplit);
}

// Round 7
// 158.885 us; speedup vs baseline: 11.5263x; 1.0336x over previous
//
#include <hip/hip_runtime.h>
#include <math.h>

// Problem constants (match reference)
#define BATCH 1024
#define NV    64      // N_VARS
#define MC    256     // M_CLAUSES
#define KD    12      // K_DIM
#define PI_F  3.14159265358979323846f

// ws/LDS layout (floats):
//   NR rows 64x68: row q = C-row of var nv(q) = (q+1)%64+1, slot j = C[nv][j+1]
//   c0N[64]  at C0OFF : C[nv(q)][0]
//   DgA[64]  at DGAOFF: DgA[v-1] = C[v][prev1(v)]  (prev1(1)=64)
//   DgB[64]  at DGBOFF: DgB[v-1] = C[v][prev2(v)]  (prev2(1)=63, prev2(2)=64)
#define CBUF   4544
#define C0OFF  4352
#define DGAOFF 4416
#define DGBOFF 4480

// ---- DPP add helpers (bound_ctrl=true -> fuses to v_add_f32_dpp) -----------
// 0xB1 quad_perm xor1, 0x4E quad_perm xor2, 0x124 row_ror:4, 0x128 row_ror:8,
// 0x142 row_bcast15, 0x143 row_bcast31.
template <int CTRL>
__device__ __forceinline__ float dpp_addf(float x) {
  int y = __builtin_amdgcn_update_dpp(0, __float_as_int(x), CTRL, 0xF, 0xF, true);
  return x + __int_as_float(y);
}
__device__ __forceinline__ float allreduce16(float x) {
  x = dpp_addf<0xB1>(x);
  x = dpp_addf<0x4E>(x);
  x = dpp_addf<0x124>(x);
  x = dpp_addf<0x128>(x);
  return x;
}
__device__ __forceinline__ float readlane63(float x) {
  return __int_as_float(__builtin_amdgcn_readlane(__float_as_int(x), 63));
}

// ---- Kernel 1: Gram rows (next-consumption order) + c0/dgA/dgB tables ------
__global__ void compute_C_kernel(const float* __restrict__ S,
                                 const float* __restrict__ w,
                                 float* __restrict__ Cg, int nsplit) {
  const int q = blockIdx.x;
  const int mc = blockIdx.y;
  const int j = threadIdx.x;  // column 0..64
  if (j > NV) return;
  const int v = (q + 1) % 64 + 1;
  const int mlen = MC / nsplit;
  const int m0 = mc * mlen;
  float a0 = 0.f, a1 = 0.f, a2 = 0.f, a3 = 0.f;
  for (int m = m0; m < m0 + mlen; m += 4) {
    const float w0 = w[m], w1 = w[m + 1], w2 = w[m + 2], w3 = w[m + 3];
    a0 = fmaf(S[(m + 0) * (NV + 1) + v] * w0 * w0, S[(m + 0) * (NV + 1) + j], a0);
    a1 = fmaf(S[(m + 1) * (NV + 1) + v] * w1 * w1, S[(m + 1) * (NV + 1) + j], a1);
    a2 = fmaf(S[(m + 2) * (NV + 1) + v] * w2 * w2, S[(m + 2) * (NV + 1) + j], a2);
    a3 = fmaf(S[(m + 3) * (NV + 1) + v] * w3 * w3, S[(m + 3) * (NV + 1) + j], a3);
  }
  const float acc = (a0 + a1) + (a2 + a3);
  float* buf = Cg + mc * CBUF;
  if (j == 0) buf[C0OFF + q] = acc;
  else        buf[q * 68 + (j - 1)] = acc;
  const int p1 = (v == 1) ? 64 : (v - 1);
  const int p2 = (v == 1) ? 63 : (v == 2) ? 64 : (v - 2);
  if (j == p1) buf[DGAOFF + (v - 1)] = acc;
  if (j == p2) buf[DGBOFF + (v - 1)] = acc;
}

// ---- Kernel 2: two-column-deferred, writeback-delayed mixing ---------------
// Block = 256 thr = 4 waves = 4 batches, shared LDS C. Wave: kq = l>>4 owns
// k-triple {3kq..3kq+2}; n16 = l&15 owns vars 4*n16+1..4*n16+4 (V[4][3]).
// Stream of steps i=1..64 repeated max_iter times. Carried state (replicated
// across the 16-lane row): P[j] = Q_i (dot for step i missing cols i-1,i-2),
// vp1[j] = u_{i-1}, vp2[j] = u_{i-2}.
// Step i body (source order matters for register dataflow):
//   B: Q_{i+1} = butterfly( C[i+1][cols] * V ), cols {i-1,i,i+1} zeroed.
//      V regs here were last written at step i-1 (u_{i-2}) -> B-chain spans
//      3 steps, off the critical path.
//   A: g = P + DgA[i]*vp1 + DgB[i]*vp2 -> n2 (2 DPP bcast + readlane) ->
//      v_new = -g * rsq(max(n2,1e-16)). Pure recurrence ~48cy/step.
//   C: delayed writeback of u_{i-1} (in vp1) into owner lane's V slot.
//   rotate: vp2=vp1, vp1=v_new, P=Q.
__global__ __launch_bounds__(256, 1) void mixing_kernel(
    const float* __restrict__ z, const float* __restrict__ r,
    const float* __restrict__ Cg, const int* __restrict__ max_iter_p,
    float* __restrict__ out, int nsplit) {
  __shared__ float Ls[CBUF];  // 18176 B

  const int t = threadIdx.x;
  const int l = t & 63;
  const int kq = l >> 4;
  const int n16 = l & 15;
  const int b = blockIdx.x * 4 + (t >> 6);
  const int max_iter = max_iter_p[0];

  // stage (and m-split-reduce) C into LDS
  {
    const float4* src = (const float4*)Cg;
    float4* dst = (float4*)Ls;
    for (int idx = t; idx < CBUF / 4; idx += 256) {
      float4 a = src[idx];
      for (int u = 1; u < nsplit; ++u) {
        const float4 p = src[u * (CBUF / 4) + idx];
        a.x += p.x; a.y += p.y; a.z += p.z; a.w += p.w;
      }
      dst[idx] = a;
    }
  }

  const float row0 = (kq == 0) ? 1.f : 0.f;

  // ---- init: V[n] = -cos(pi z) e0 + sin(pi z) * r_perp_hat ----
  float V[4][3];
  #pragma unroll
  for (int s = 0; s < 4; ++s) {
    const int n = 4 * n16 + s;
    const float zv = z[b * NV + n];
    float rp[3];
    float ssp = 0.f;
    #pragma unroll
    for (int j = 0; j < 3; ++j) {
      const int k = 3 * kq + j;
      rp[j] = (k == 0) ? 0.f : r[(b * NV + n) * KD + k];
      ssp = fmaf(rp[j], rp[j], ssp);
    }
    ssp += __shfl_xor(ssp, 16, 64);
    ssp += __shfl_xor(ssp, 32, 64);
    const float inv = 1.f / fmaxf(sqrtf(ssp), 1e-8f);
    float sn, cs;
    sincosf(PI_F * zv, &sn, &cs);
    #pragma unroll
    for (int j = 0; j < 3; ++j) {
      const int k = 3 * kq + j;
      V[s][j] = (k == 0) ? -cs : sn * rp[j] * inv;
    }
  }

  __syncthreads();

  const float4* C4   = (const float4*)Ls;               // [q*17 + n16]
  const float4* C04  = (const float4*)(Ls + C0OFF);     // [g]
  const float4* DgA4 = (const float4*)(Ls + DGAOFF);    // [g]
  const float4* DgB4 = (const float4*)(Ls + DGBOFF);    // [g]

  float P[3], vp1[3], vp2[3];

  // ---- prologue: Q_1 from row NR[63] (= C[1]), zero slots {62,63,0};
  //      vp1 = V_init[var64] (slot63), vp2 = V_init[var63] (slot62) ----
  {
    float4 ce = C4[63 * 17 + n16];
    const float c0 = Ls[C0OFF + 63];
    const bool l15 = (n16 == 15), l0 = (n16 == 0);
    ce.z = l15 ? 0.f : ce.z;
    ce.w = l15 ? 0.f : ce.w;
    ce.x = l0 ? 0.f : ce.x;
    float q0 = ce.x * V[0][0];
    float q1 = ce.x * V[0][1];
    float q2 = ce.x * V[0][2];
    q0 = fmaf(ce.y, V[1][0], q0); q1 = fmaf(ce.y, V[1][1], q1); q2 = fmaf(ce.y, V[1][2], q2);
    q0 = fmaf(ce.z, V[2][0], q0); q1 = fmaf(ce.z, V[2][1], q1); q2 = fmaf(ce.z, V[2][2], q2);
    q0 = fmaf(ce.w, V[3][0], q0); q1 = fmaf(ce.w, V[3][1], q1); q2 = fmaf(ce.w, V[3][2], q2);
    q0 = allreduce16(q0);
    q1 = allreduce16(q1);
    q2 = allreduce16(q2);
    q0 = fmaf(row0, c0, q0);
    P[0] = q0; P[1] = q1; P[2] = q2;
    const int src = l | 15;  // this row's lane 15
    #pragma unroll
    for (int j = 0; j < 3; ++j) {
      vp1[j] = __shfl(V[3][j], src, 64);
      vp2[j] = __shfl(V[2][j], src, 64);
    }
  }

  float4 cbA[4], cbB[4], c0A, c0B, daA, daB, dbA, dbB;

  auto prefetch = [&](float4 cb[4], float4& c0b, float4& dab, float4& dbb, int g) {
    #pragma unroll
    for (int s = 0; s < 4; ++s) cb[s] = C4[(4 * g + s) * 17 + n16];
    c0b = C04[g];
    dab = DgA4[g];
    dbb = DgB4[g];
  };

  auto do_group = [&](int ii, const float4 cb[4], const float4& c0b,
                      const float4& dab, const float4& dbb) {
    const bool own  = (n16 == ii);
    const bool ownP = (n16 == ((ii + 15) & 15));
    const bool ownN = (n16 == ((ii + 1) & 15));
    const float* c0p = &c0b.x;
    const float* dap = &dab.x;
    const float* dbp = &dbb.x;
    #pragma unroll
    for (int s = 0; s < 4; ++s) {
      // ---- Phase B: build Q for step i+1 from row C[i+1] ----
      float4 ce = cb[s];
      if (s == 0) { ce.w = ownP ? 0.f : ce.w; ce.x = own ? 0.f : ce.x; ce.y = own ? 0.f : ce.y; }
      if (s == 1) { ce.x = own ? 0.f : ce.x;  ce.y = own ? 0.f : ce.y; ce.z = own ? 0.f : ce.z; }
      if (s == 2) { ce.y = own ? 0.f : ce.y;  ce.z = own ? 0.f : ce.z; ce.w = own ? 0.f : ce.w; }
      if (s == 3) { ce.z = own ? 0.f : ce.z;  ce.w = own ? 0.f : ce.w; ce.x = ownN ? 0.f : ce.x; }
      float q0 = ce.x * V[0][0];
      float q1 = ce.x * V[0][1];
      float q2 = ce.x * V[0][2];
      q0 = fmaf(ce.y, V[1][0], q0); q1 = fmaf(ce.y, V[1][1], q1); q2 = fmaf(ce.y, V[1][2], q2);
      q0 = fmaf(ce.z, V[2][0], q0); q1 = fmaf(ce.z, V[2][1], q1); q2 = fmaf(ce.z, V[2][2], q2);
      q0 = fmaf(ce.w, V[3][0], q0); q1 = fmaf(ce.w, V[3][1], q1); q2 = fmaf(ce.w, V[3][2], q2);
      q0 = allreduce16(q0);
      q1 = allreduce16(q1);
      q2 = allreduce16(q2);
      q0 = fmaf(row0, c0p[s], q0);

      // ---- Phase A: finish step i (the true recurrence) ----
      float g0 = fmaf(dbp[s], vp2[0], P[0]);
      float g1 = fmaf(dbp[s], vp2[1], P[1]);
      float g2 = fmaf(dbp[s], vp2[2], P[2]);
      g0 = fmaf(dap[s], vp1[0], g0);
      g1 = fmaf(dap[s], vp1[1], g1);
      g2 = fmaf(dap[s], vp1[2], g2);
      const float t0 = g0 * g0, t1 = g1 * g1, t2 = g2 * g2;
      float n2p = (t0 + t1) + t2;
      n2p = dpp_addf<0x142>(n2p);  // cross-row partials
      n2p = dpp_addf<0x143>(n2p);  // lane63 = total
      const float n2 = readlane63(n2p);
      const float inv = __builtin_amdgcn_rsqf(fmaxf(n2, 1e-16f));
      const float v0 = -g0 * inv, v1 = -g1 * inv, v2 = -g2 * inv;

      // ---- Phase C: delayed writeback of u_{i-1} (held in vp1) ----
      if (s == 0) {
        V[3][0] = ownP ? vp1[0] : V[3][0];
        V[3][1] = ownP ? vp1[1] : V[3][1];
        V[3][2] = ownP ? vp1[2] : V[3][2];
      } else {
        V[s - 1][0] = own ? vp1[0] : V[s - 1][0];
        V[s - 1][1] = own ? vp1[1] : V[s - 1][1];
        V[s - 1][2] = own ? vp1[2] : V[s - 1][2];
      }

      // rotate carried state (renamed by unroll)
      vp2[0] = vp1[0]; vp2[1] = vp1[1]; vp2[2] = vp1[2];
      vp1[0] = v0;     vp1[1] = v1;     vp1[2] = v2;
      P[0] = q0; P[1] = q1; P[2] = q2;
    }
  };

  prefetch(cbA, c0A, daA, dbA, 0);

  // ---- sweeps (groups of 4 steps; ping-pong prefetch, unroll by 2) ----
  for (int it = 0; it < max_iter; ++it) {
    for (int ih = 0; ih < 8; ++ih) {
      prefetch(cbB, c0B, daB, dbB, 2 * ih + 1);
      do_group(2 * ih, cbA, c0A, daA, dbA);
      prefetch(cbA, c0A, daA, dbA, (2 * ih + 2) & 15);
      do_group(2 * ih + 1, cbB, c0B, daB, dbB);
    }
  }

  // final pending writeback: u_64 still in vp1 -> slot 63 (lane 15, V[3])
  {
    const bool l15 = (n16 == 15);
    V[3][0] = l15 ? vp1[0] : V[3][0];
    V[3][1] = l15 ? vp1[1] : V[3][1];
    V[3][2] = l15 ? vp1[2] : V[3][2];
  }

  // ---- epilogue: kq==0 lanes hold k=0 ----
  if (kq == 0) {
    float4 o;
    float* op = &o.x;
    #pragma unroll
    for (int s = 0; s < 4; ++s) {
      float cv = -V[s][0];
      cv = fminf(fmaxf(cv, -1.f + 1e-6f), 1.f - 1e-6f);
      op[s] = acosf(cv) * (1.f / PI_F);
    }
    ((float4*)(out + b * NV))[n16] = o;
  }
}

extern "C" void kernel_launch(void* const* d_in, const int* in_sizes, int n_in,
                              void* d_out, int out_size, void* d_ws, size_t ws_size,
                              hipStream_t stream) {
  const float* z = (const float*)d_in[0];
  const float* S = (const float*)d_in[1];
  const float* w = (const float*)d_in[2];
  const float* r = (const float*)d_in[3];
  const int* max_iter = (const int*)d_in[4];
  float* Cg = (float*)d_ws;

  const int nsplit = (ws_size >= (size_t)4 * CBUF * 4) ? 4 : 1;
  compute_C_kernel<<<dim3(NV, nsplit), 128, 0, stream>>>(S, w, Cg, nsplit);
  mixing_kernel<<<BATCH / 4, 256, 0, stream>>>(z, r, Cg, max_iter,
                                               (float*)d_out, nsplit);
}

// Round 8
// 153.861 us; speedup vs baseline: 11.9027x; 1.0327x over previous
//
#include <hip/hip_runtime.h>
#include <math.h>

// Problem constants (match reference)
#define BATCH 1024
#define NV    64      // N_VARS
#define MC    256     // M_CLAUSES
#define KD    12      // K_DIM
#define PI_F  3.14159265358979323846f

// ws/LDS layout (floats):
//   NR rows 64x68: row q = C-row of var v = nv(q) = (q+1)%64+1, slot j =
//     C[v][j+1], with cols {v-2, v-1, v} (wrapped in 1..64) PRE-ZEROED.
//   c0N[64]  at C0OFF : C[v][0]
//   DgA[64]  at DGAOFF: DgA[v-1] = C[v][prev1(v)]  (prev1(1)=64)
//   DgB[64]  at DGBOFF: DgB[v-1] = C[v][prev2(v)]  (prev2(1)=63, prev2(2)=64)
#define CBUF   4544
#define C0OFF  4352
#define DGAOFF 4416
#define DGBOFF 4480

// ---- DPP add helpers (bound_ctrl=true -> GCNDPPCombine fuses to
// v_add_f32_dpp). 0xB1 quad_perm xor1, 0x4E quad_perm xor2, 0x124 row_ror:4,
// 0x128 row_ror:8, 0x142 row_bcast15, 0x143 row_bcast31.
template <int CTRL>
__device__ __forceinline__ float dpp_addf(float x) {
  int y = __builtin_amdgcn_update_dpp(0, __float_as_int(x), CTRL, 0xF, 0xF, true);
  return x + __int_as_float(y);
}
__device__ __forceinline__ float allreduce16(float x) {
  x = dpp_addf<0xB1>(x);
  x = dpp_addf<0x4E>(x);
  x = dpp_addf<0x124>(x);
  x = dpp_addf<0x128>(x);
  return x;
}
__device__ __forceinline__ float readlane63(float x) {
  return __int_as_float(__builtin_amdgcn_readlane(__float_as_int(x), 63));
}

// ---- Kernel 1: Gram rows (pre-zeroed excl. columns) + c0/dgA/dgB tables ----
__global__ void compute_C_kernel(const float* __restrict__ S,
                                 const float* __restrict__ w,
                                 float* __restrict__ Cg, int nsplit) {
  const int q = blockIdx.x;
  const int mc = blockIdx.y;
  const int j = threadIdx.x;  // column 0..64
  if (j > NV) return;
  const int v = (q + 1) % 64 + 1;
  const int mlen = MC / nsplit;
  const int m0 = mc * mlen;
  float a0 = 0.f, a1 = 0.f, a2 = 0.f, a3 = 0.f;
  for (int m = m0; m < m0 + mlen; m += 4) {
    const float w0 = w[m], w1 = w[m + 1], w2 = w[m + 2], w3 = w[m + 3];
    a0 = fmaf(S[(m + 0) * (NV + 1) + v] * w0 * w0, S[(m + 0) * (NV + 1) + j], a0);
    a1 = fmaf(S[(m + 1) * (NV + 1) + v] * w1 * w1, S[(m + 1) * (NV + 1) + j], a1);
    a2 = fmaf(S[(m + 2) * (NV + 1) + v] * w2 * w2, S[(m + 2) * (NV + 1) + j], a2);
    a3 = fmaf(S[(m + 3) * (NV + 1) + v] * w3 * w3, S[(m + 3) * (NV + 1) + j], a3);
  }
  const float acc = (a0 + a1) + (a2 + a3);
  float* buf = Cg + mc * CBUF;
  const int p1 = (v == 1) ? 64 : (v - 1);
  const int p2 = (v == 1) ? 63 : (v == 2) ? 64 : (v - 2);
  if (j == 0) buf[C0OFF + q] = acc;
  if (j == p1) buf[DGAOFF + (v - 1)] = acc;
  if (j == p2) buf[DGBOFF + (v - 1)] = acc;
  if (j > 0) {
    // pre-zero the columns Phase B must exclude: {v-2, v-1, v}
    const float st = (j == v || j == p1 || j == p2) ? 0.f : acc;
    buf[q * 68 + (j - 1)] = st;
  }
}

// ---- Kernel 2: two-column-deferred mixing + per-sweep early exit -----------
// Block = 256 thr = 4 waves = 4 batches, shared LDS C. Wave: kq = l>>4 owns
// k-triple {3kq..3kq+2}; n16 = l&15 owns vars 4*n16+1..4*n16+4 (V[4][3]).
// Carried: P = Q_i (dot missing cols i-1,i-2), vp1 = u_{i-1}, vp2 = u_{i-2}.
// Step i: B) Q_{i+1} from pre-zeroed row (no masks); A) g = P + DgA*vp1 +
// DgB*vp2 -> norm -> v_new; C) delayed writeback of u_{i-1}.
// Early exit: snapshot V per sweep; if no lane moved > 1e-6, stop sweeping
// (remaining sweeps would move output < ~2e-3 << 1.86e-2 threshold).
__global__ __launch_bounds__(256, 1) void mixing_kernel(
    const float* __restrict__ z, const float* __restrict__ r,
    const float* __restrict__ Cg, const int* __restrict__ max_iter_p,
    float* __restrict__ out, int nsplit) {
  __shared__ float Ls[CBUF];  // 18176 B

  const int t = threadIdx.x;
  const int l = t & 63;
  const int kq = l >> 4;
  const int n16 = l & 15;
  const int b = blockIdx.x * 4 + (t >> 6);
  const int max_iter = max_iter_p[0];

  // stage (and m-split-reduce) C into LDS
  {
    const float4* src = (const float4*)Cg;
    float4* dst = (float4*)Ls;
    for (int idx = t; idx < CBUF / 4; idx += 256) {
      float4 a = src[idx];
      for (int u = 1; u < nsplit; ++u) {
        const float4 p = src[u * (CBUF / 4) + idx];
        a.x += p.x; a.y += p.y; a.z += p.z; a.w += p.w;
      }
      dst[idx] = a;
    }
  }

  const float row0 = (kq == 0) ? 1.f : 0.f;

  // ---- init: V[n] = -cos(pi z) e0 + sin(pi z) * r_perp_hat ----
  float V[4][3];
  #pragma unroll
  for (int s = 0; s < 4; ++s) {
    const int n = 4 * n16 + s;
    const float zv = z[b * NV + n];
    float rp[3];
    float ssp = 0.f;
    #pragma unroll
    for (int j = 0; j < 3; ++j) {
      const int k = 3 * kq + j;
      rp[j] = (k == 0) ? 0.f : r[(b * NV + n) * KD + k];
      ssp = fmaf(rp[j], rp[j], ssp);
    }
    ssp += __shfl_xor(ssp, 16, 64);
    ssp += __shfl_xor(ssp, 32, 64);
    const float inv = 1.f / fmaxf(sqrtf(ssp), 1e-8f);
    float sn, cs;
    sincosf(PI_F * zv, &sn, &cs);
    #pragma unroll
    for (int j = 0; j < 3; ++j) {
      const int k = 3 * kq + j;
      V[s][j] = (k == 0) ? -cs : sn * rp[j] * inv;
    }
  }

  __syncthreads();

  const float4* C4   = (const float4*)Ls;               // [q*17 + n16]
  const float4* C04  = (const float4*)(Ls + C0OFF);     // [g]
  const float4* DgA4 = (const float4*)(Ls + DGAOFF);    // [g]
  const float4* DgB4 = (const float4*)(Ls + DGBOFF);    // [g]

  float P[3], vp1[3], vp2[3];

  // ---- prologue: Q_1 from pre-zeroed row NR[63] (= C[1]);
  //      vp1 = V_init[var64] (slot63), vp2 = V_init[var63] (slot62) ----
  {
    const float4 ce = C4[63 * 17 + n16];
    const float c0 = Ls[C0OFF + 63];
    float q0 = ce.x * V[0][0];
    float q1 = ce.x * V[0][1];
    float q2 = ce.x * V[0][2];
    q0 = fmaf(ce.y, V[1][0], q0); q1 = fmaf(ce.y, V[1][1], q1); q2 = fmaf(ce.y, V[1][2], q2);
    q0 = fmaf(ce.z, V[2][0], q0); q1 = fmaf(ce.z, V[2][1], q1); q2 = fmaf(ce.z, V[2][2], q2);
    q0 = fmaf(ce.w, V[3][0], q0); q1 = fmaf(ce.w, V[3][1], q1); q2 = fmaf(ce.w, V[3][2], q2);
    q0 = allreduce16(q0);
    q1 = allreduce16(q1);
    q2 = allreduce16(q2);
    q0 = fmaf(row0, c0, q0);
    P[0] = q0; P[1] = q1; P[2] = q2;
    const int src = l | 15;  // this row's lane 15
    #pragma unroll
    for (int j = 0; j < 3; ++j) {
      vp1[j] = __shfl(V[3][j], src, 64);
      vp2[j] = __shfl(V[2][j], src, 64);
    }
  }

  float4 cbA[4], cbB[4], c0A, c0B, daA, daB, dbA, dbB;

  auto prefetch = [&](float4 cb[4], float4& c0b, float4& dab, float4& dbb, int g) {
    #pragma unroll
    for (int s = 0; s < 4; ++s) cb[s] = C4[(4 * g + s) * 17 + n16];
    c0b = C04[g];
    dab = DgA4[g];
    dbb = DgB4[g];
  };

  auto do_group = [&](int ii, const float4 cb[4], const float4& c0b,
                      const float4& dab, const float4& dbb) {
    const bool own  = (n16 == ii);
    const bool ownP = (n16 == ((ii + 15) & 15));
    const float* c0p = &c0b.x;
    const float* dap = &dab.x;
    const float* dbp = &dbb.x;
    #pragma unroll
    for (int s = 0; s < 4; ++s) {
      // ---- Phase B: Q for step i+1 from pre-zeroed row C[i+1] ----
      const float4 ce = cb[s];
      float q0 = ce.x * V[0][0];
      float q1 = ce.x * V[0][1];
      float q2 = ce.x * V[0][2];
      q0 = fmaf(ce.y, V[1][0], q0); q1 = fmaf(ce.y, V[1][1], q1); q2 = fmaf(ce.y, V[1][2], q2);
      q0 = fmaf(ce.z, V[2][0], q0); q1 = fmaf(ce.z, V[2][1], q1); q2 = fmaf(ce.z, V[2][2], q2);
      q0 = fmaf(ce.w, V[3][0], q0); q1 = fmaf(ce.w, V[3][1], q1); q2 = fmaf(ce.w, V[3][2], q2);
      q0 = allreduce16(q0);
      q1 = allreduce16(q1);
      q2 = allreduce16(q2);
      q0 = fmaf(row0, c0p[s], q0);

      // ---- Phase A: finish step i (the true recurrence) ----
      float g0 = fmaf(dbp[s], vp2[0], P[0]);
      float g1 = fmaf(dbp[s], vp2[1], P[1]);
      float g2 = fmaf(dbp[s], vp2[2], P[2]);
      g0 = fmaf(dap[s], vp1[0], g0);
      g1 = fmaf(dap[s], vp1[1], g1);
      g2 = fmaf(dap[s], vp1[2], g2);
      float n2p = g0 * g0;
      n2p = fmaf(g1, g1, n2p);
      n2p = fmaf(g2, g2, n2p);
      n2p = dpp_addf<0x142>(n2p);  // cross-row partials
      n2p = dpp_addf<0x143>(n2p);  // lane63 = total
      const float n2 = readlane63(n2p);
      const float inv = __builtin_amdgcn_rsqf(fmaxf(n2, 1e-16f));
      const float v0 = -g0 * inv, v1 = -g1 * inv, v2 = -g2 * inv;

      // ---- Phase C: delayed writeback of u_{i-1} (held in vp1) ----
      if (s == 0) {
        V[3][0] = ownP ? vp1[0] : V[3][0];
        V[3][1] = ownP ? vp1[1] : V[3][1];
        V[3][2] = ownP ? vp1[2] : V[3][2];
      } else {
        V[s - 1][0] = own ? vp1[0] : V[s - 1][0];
        V[s - 1][1] = own ? vp1[1] : V[s - 1][1];
        V[s - 1][2] = own ? vp1[2] : V[s - 1][2];
      }

      // rotate carried state (renamed by unroll)
      vp2[0] = vp1[0]; vp2[1] = vp1[1]; vp2[2] = vp1[2];
      vp1[0] = v0;     vp1[1] = v1;     vp1[2] = v2;
      P[0] = q0; P[1] = q1; P[2] = q2;
    }
  };

  prefetch(cbA, c0A, daA, dbA, 0);

  // ---- sweeps with per-sweep convergence early-exit ----
  for (int it = 0; it < max_iter; ++it) {
    float Vs[4][3];
    #pragma unroll
    for (int s = 0; s < 4; ++s) {
      Vs[s][0] = V[s][0]; Vs[s][1] = V[s][1]; Vs[s][2] = V[s][2];
    }
    for (int ih = 0; ih < 8; ++ih) {
      prefetch(cbB, c0B, daB, dbB, 2 * ih + 1);
      do_group(2 * ih, cbA, c0A, daA, dbA);
      prefetch(cbA, c0A, daA, dbA, (2 * ih + 2) & 15);
      do_group(2 * ih + 1, cbB, c0B, daB, dbB);
    }
    float d = 0.f;
    #pragma unroll
    for (int s = 0; s < 4; ++s) {
      d = fmaxf(d, fabsf(V[s][0] - Vs[s][0]));
      d = fmaxf(d, fabsf(V[s][1] - Vs[s][1]));
      d = fmaxf(d, fabsf(V[s][2] - Vs[s][2]));
    }
    if (__ballot(d > 1e-6f) == 0ull) break;  // wave-converged: stop sweeping
  }

  // final pending writeback: u_64 still in vp1 -> slot 63 (lane 15, V[3])
  {
    const bool l15 = (n16 == 15);
    V[3][0] = l15 ? vp1[0] : V[3][0];
    V[3][1] = l15 ? vp1[1] : V[3][1];
    V[3][2] = l15 ? vp1[2] : V[3][2];
  }

  // ---- epilogue: kq==0 lanes hold k=0 ----
  if (kq == 0) {
    float4 o;
    float* op = &o.x;
    #pragma unroll
    for (int s = 0; s < 4; ++s) {
      float cv = -V[s][0];
      cv = fminf(fmaxf(cv, -1.f + 1e-6f), 1.f - 1e-6f);
      op[s] = acosf(cv) * (1.f / PI_F);
    }
    ((float4*)(out + b * NV))[n16] = o;
  }
}

extern "C" void kernel_launch(void* const* d_in, const int* in_sizes, int n_in,
                              void* d_out, int out_size, void* d_ws, size_t ws_size,
                              hipStream_t stream) {
  const float* z = (const float*)d_in[0];
  const float* S = (const float*)d_in[1];
  const float* w = (const float*)d_in[2];
  const float* r = (const float*)d_in[3];
  const int* max_iter = (const int*)d_in[4];
  float* Cg = (float*)d_ws;

  const int nsplit = (ws_size >= (size_t)8 * CBUF * 4) ? 8
                   : (ws_size >= (size_t)4 * CBUF * 4) ? 4 : 1;
  compute_C_kernel<<<dim3(NV, nsplit), 128, 0, stream>>>(S, w, Cg, nsplit);
  mixing_kernel<<<BATCH / 4, 256, 0, stream>>>(z, r, Cg, max_iter,
                                               (float*)d_out, nsplit);
}

// Round 9
// 153.716 us; speedup vs baseline: 11.9139x; 1.0009x over previous
//
#include <hip/hip_runtime.h>
#include <math.h>

// Problem constants (match reference)
#define BATCH 1024
#define NV    64      // N_VARS
#define MC    256     // M_CLAUSES
#define KD    12      // K_DIM
#define PI_F  3.14159265358979323846f

// ws/LDS layout (floats):
//   NR rows 64x68: row q = C-row of var v = nv(q) = (q+1)%64+1, slot j =
//     C[v][j+1], with cols {v-2, v-1, v} (wrapped in 1..64) PRE-ZEROED.
//   c0N[64]  at C0OFF : C[v][0]
//   DgA[64]  at DGAOFF: DgA[v-1] = C[v][prev1(v)]  (prev1(1)=64)
//   DgB[64]  at DGBOFF: DgB[v-1] = C[v][prev2(v)]  (prev2(1)=63, prev2(2)=64)
#define CBUF   4544
#define C0OFF  4352
#define DGAOFF 4416
#define DGBOFF 4480

// ---- DPP add helpers (bound_ctrl=true -> GCNDPPCombine fuses to
// v_add_f32_dpp). 0xB1 quad_perm xor1, 0x4E quad_perm xor2, 0x124 row_ror:4,
// 0x128 row_ror:8, 0x142 row_bcast15, 0x143 row_bcast31.
template <int CTRL>
__device__ __forceinline__ float dpp_addf(float x) {
  int y = __builtin_amdgcn_update_dpp(0, __float_as_int(x), CTRL, 0xF, 0xF, true);
  return x + __int_as_float(y);
}
__device__ __forceinline__ float allreduce16(float x) {
  x = dpp_addf<0xB1>(x);
  x = dpp_addf<0x4E>(x);
  x = dpp_addf<0x124>(x);
  x = dpp_addf<0x128>(x);
  return x;
}
__device__ __forceinline__ float readlane63(float x) {
  return __int_as_float(__builtin_amdgcn_readlane(__float_as_int(x), 63));
}

// ---- Kernel 1: Gram rows (pre-zeroed excl. columns) + c0/dgA/dgB tables ----
__global__ void compute_C_kernel(const float* __restrict__ S,
                                 const float* __restrict__ w,
                                 float* __restrict__ Cg, int nsplit) {
  const int q = blockIdx.x;
  const int mc = blockIdx.y;
  const int j = threadIdx.x;  // column 0..64
  if (j > NV) return;
  const int v = (q + 1) % 64 + 1;
  const int mlen = MC / nsplit;
  const int m0 = mc * mlen;
  float a0 = 0.f, a1 = 0.f, a2 = 0.f, a3 = 0.f;
  for (int m = m0; m < m0 + mlen; m += 4) {
    const float w0 = w[m], w1 = w[m + 1], w2 = w[m + 2], w3 = w[m + 3];
    a0 = fmaf(S[(m + 0) * (NV + 1) + v] * w0 * w0, S[(m + 0) * (NV + 1) + j], a0);
    a1 = fmaf(S[(m + 1) * (NV + 1) + v] * w1 * w1, S[(m + 1) * (NV + 1) + j], a1);
    a2 = fmaf(S[(m + 2) * (NV + 1) + v] * w2 * w2, S[(m + 2) * (NV + 1) + j], a2);
    a3 = fmaf(S[(m + 3) * (NV + 1) + v] * w3 * w3, S[(m + 3) * (NV + 1) + j], a3);
  }
  const float acc = (a0 + a1) + (a2 + a3);
  float* buf = Cg + mc * CBUF;
  const int p1 = (v == 1) ? 64 : (v - 1);
  const int p2 = (v == 1) ? 63 : (v == 2) ? 64 : (v - 2);
  if (j == 0) buf[C0OFF + q] = acc;
  if (j == p1) buf[DGAOFF + (v - 1)] = acc;
  if (j == p2) buf[DGBOFF + (v - 1)] = acc;
  if (j > 0) {
    // pre-zero the columns Phase B must exclude: {v-2, v-1, v}
    const float st = (j == v || j == p1 || j == p2) ? 0.f : acc;
    buf[q * 68 + (j - 1)] = st;
  }
}

// ---- Kernel 2: two-column-deferred mixing, hand-scheduled step body --------
// Block = 256 thr = 4 waves = 4 batches, shared LDS C. Wave: kq = l>>4 owns
// k-triple {3kq..3kq+2}; n16 = l&15 owns vars 4*n16+1..4*n16+4 (V[4][3]).
// Carried: P = Q_i (dot missing cols i-1,i-2), vp1 = u_{i-1}, vp2 = u_{i-2}.
// Step body (scheduling-aware order; arithmetic identical to R8):
//   A-start: g = P + DgB*vp2 + DgA*vp1; n2 partial (the true recurrence)
//   B-products: 12 fma from pre-zeroed row C[i+1] (fills A's fma gaps)
//   cross-lane: A's 2 bcast hops + B's 3 butterflies interleaved hop-major
//     (>=3 independent DPP ops between dependent hops -> no hazard stalls)
//   A-tail: readlane -> rsq -> muls, braided between B's last hops
//   C: delayed writeback of u_{i-1}; rotate carried state.
__global__ __launch_bounds__(256, 1) void mixing_kernel(
    const float* __restrict__ z, const float* __restrict__ r,
    const float* __restrict__ Cg, const int* __restrict__ max_iter_p,
    float* __restrict__ out, int nsplit) {
  __shared__ float Ls[CBUF];  // 18176 B

  const int t = threadIdx.x;
  const int l = t & 63;
  const int kq = l >> 4;
  const int n16 = l & 15;
  const int b = blockIdx.x * 4 + (t >> 6);
  const int max_iter = max_iter_p[0];

  // stage (and m-split-reduce) C into LDS
  {
    const float4* src = (const float4*)Cg;
    float4* dst = (float4*)Ls;
    for (int idx = t; idx < CBUF / 4; idx += 256) {
      float4 a = src[idx];
      for (int u = 1; u < nsplit; ++u) {
        const float4 p = src[u * (CBUF / 4) + idx];
        a.x += p.x; a.y += p.y; a.z += p.z; a.w += p.w;
      }
      dst[idx] = a;
    }
  }

  const float row0 = (kq == 0) ? 1.f : 0.f;

  // ---- init: V[n] = -cos(pi z) e0 + sin(pi z) * r_perp_hat ----
  float V[4][3];
  #pragma unroll
  for (int s = 0; s < 4; ++s) {
    const int n = 4 * n16 + s;
    const float zv = z[b * NV + n];
    float rp[3];
    float ssp = 0.f;
    #pragma unroll
    for (int j = 0; j < 3; ++j) {
      const int k = 3 * kq + j;
      rp[j] = (k == 0) ? 0.f : r[(b * NV + n) * KD + k];
      ssp = fmaf(rp[j], rp[j], ssp);
    }
    ssp += __shfl_xor(ssp, 16, 64);
    ssp += __shfl_xor(ssp, 32, 64);
    const float inv = 1.f / fmaxf(sqrtf(ssp), 1e-8f);
    float sn, cs;
    sincosf(PI_F * zv, &sn, &cs);
    #pragma unroll
    for (int j = 0; j < 3; ++j) {
      const int k = 3 * kq + j;
      V[s][j] = (k == 0) ? -cs : sn * rp[j] * inv;
    }
  }

  __syncthreads();

  const float4* C4   = (const float4*)Ls;               // [q*17 + n16]
  const float4* C04  = (const float4*)(Ls + C0OFF);     // [g]
  const float4* DgA4 = (const float4*)(Ls + DGAOFF);    // [g]
  const float4* DgB4 = (const float4*)(Ls + DGBOFF);    // [g]

  float P[3], vp1[3], vp2[3];

  // ---- prologue: Q_1 from pre-zeroed row NR[63] (= C[1]);
  //      vp1 = V_init[var64] (slot63), vp2 = V_init[var63] (slot62) ----
  {
    const float4 ce = C4[63 * 17 + n16];
    const float c0 = Ls[C0OFF + 63];
    float q0 = ce.x * V[0][0];
    float q1 = ce.x * V[0][1];
    float q2 = ce.x * V[0][2];
    q0 = fmaf(ce.y, V[1][0], q0); q1 = fmaf(ce.y, V[1][1], q1); q2 = fmaf(ce.y, V[1][2], q2);
    q0 = fmaf(ce.z, V[2][0], q0); q1 = fmaf(ce.z, V[2][1], q1); q2 = fmaf(ce.z, V[2][2], q2);
    q0 = fmaf(ce.w, V[3][0], q0); q1 = fmaf(ce.w, V[3][1], q1); q2 = fmaf(ce.w, V[3][2], q2);
    q0 = allreduce16(q0);
    q1 = allreduce16(q1);
    q2 = allreduce16(q2);
    q0 = fmaf(row0, c0, q0);
    P[0] = q0; P[1] = q1; P[2] = q2;
    const int src = l | 15;  // this row's lane 15
    #pragma unroll
    for (int j = 0; j < 3; ++j) {
      vp1[j] = __shfl(V[3][j], src, 64);
      vp2[j] = __shfl(V[2][j], src, 64);
    }
  }

  float4 cbA[4], cbB[4], c0A, c0B, daA, daB, dbA, dbB;

  auto prefetch = [&](float4 cb[4], float4& c0b, float4& dab, float4& dbb, int g) {
    #pragma unroll
    for (int s = 0; s < 4; ++s) cb[s] = C4[(4 * g + s) * 17 + n16];
    c0b = C04[g];
    dab = DgA4[g];
    dbb = DgB4[g];
  };

  auto do_group = [&](int ii, const float4 cb[4], const float4& c0b,
                      const float4& dab, const float4& dbb) {
    const bool own  = (n16 == ii);
    const bool ownP = (n16 == ((ii + 15) & 15));
    const float* c0p = &c0b.x;
    const float* dap = &dab.x;
    const float* dbp = &dbb.x;
    #pragma unroll
    for (int s = 0; s < 4; ++s) {
      const float4 ce = cb[s];

      // ---- Phase A start: the true recurrence (g, n2 partial) ----
      float g0 = fmaf(dbp[s], vp2[0], P[0]);
      float g1 = fmaf(dbp[s], vp2[1], P[1]);
      float g2 = fmaf(dbp[s], vp2[2], P[2]);
      g0 = fmaf(dap[s], vp1[0], g0);
      g1 = fmaf(dap[s], vp1[1], g1);
      g2 = fmaf(dap[s], vp1[2], g2);

      // ---- Phase B products (independent; fill A's fma latency gaps) ----
      float q0 = ce.x * V[0][0];
      float q1 = ce.x * V[0][1];
      float q2 = ce.x * V[0][2];
      q0 = fmaf(ce.y, V[1][0], q0); q1 = fmaf(ce.y, V[1][1], q1); q2 = fmaf(ce.y, V[1][2], q2);
      q0 = fmaf(ce.z, V[2][0], q0); q1 = fmaf(ce.z, V[2][1], q1); q2 = fmaf(ce.z, V[2][2], q2);
      q0 = fmaf(ce.w, V[3][0], q0); q1 = fmaf(ce.w, V[3][1], q1); q2 = fmaf(ce.w, V[3][2], q2);

      float n2p = g0 * g0;
      n2p = fmaf(g1, g1, n2p);
      n2p = fmaf(g2, g2, n2p);

      // ---- cross-lane phase: hop-major interleave (no DPP read hazards) ----
      n2p = dpp_addf<0x142>(n2p);                 // A bcast15
      q0 = dpp_addf<0xB1>(q0);                    // B hop 1
      q1 = dpp_addf<0xB1>(q1);
      q2 = dpp_addf<0xB1>(q2);
      n2p = dpp_addf<0x143>(n2p);                 // A bcast31 -> lane63 total
      q0 = dpp_addf<0x4E>(q0);                    // B hop 2
      q1 = dpp_addf<0x4E>(q1);
      q2 = dpp_addf<0x4E>(q2);
      const float n2 = readlane63(n2p);           // A tail starts
      q0 = dpp_addf<0x124>(q0);                   // B hop 3
      q1 = dpp_addf<0x124>(q1);
      q2 = dpp_addf<0x124>(q2);
      const float inv = __builtin_amdgcn_rsqf(fmaxf(n2, 1e-16f));
      q0 = dpp_addf<0x128>(q0);                   // B hop 4
      q1 = dpp_addf<0x128>(q1);
      q2 = dpp_addf<0x128>(q2);
      const float v0 = -g0 * inv, v1 = -g1 * inv, v2 = -g2 * inv;
      q0 = fmaf(row0, c0p[s], q0);                // e0 term -> k=0 only

      // ---- Phase C: delayed writeback of u_{i-1} (held in vp1) ----
      if (s == 0) {
        V[3][0] = ownP ? vp1[0] : V[3][0];
        V[3][1] = ownP ? vp1[1] : V[3][1];
        V[3][2] = ownP ? vp1[2] : V[3][2];
      } else {
        V[s - 1][0] = own ? vp1[0] : V[s - 1][0];
        V[s - 1][1] = own ? vp1[1] : V[s - 1][1];
        V[s - 1][2] = own ? vp1[2] : V[s - 1][2];
      }

      // rotate carried state (renamed by unroll)
      vp2[0] = vp1[0]; vp2[1] = vp1[1]; vp2[2] = vp1[2];
      vp1[0] = v0;     vp1[1] = v1;     vp1[2] = v2;
      P[0] = q0; P[1] = q1; P[2] = q2;
    }
  };

  prefetch(cbA, c0A, daA, dbA, 0);

  // ---- sweeps (groups of 4 steps; ping-pong prefetch, unroll by 2) ----
  for (int it = 0; it < max_iter; ++it) {
    for (int ih = 0; ih < 8; ++ih) {
      prefetch(cbB, c0B, daB, dbB, 2 * ih + 1);
      do_group(2 * ih, cbA, c0A, daA, dbA);
      prefetch(cbA, c0A, daA, dbA, (2 * ih + 2) & 15);
      do_group(2 * ih + 1, cbB, c0B, daB, dbB);
    }
  }

  // final pending writeback: u_64 still in vp1 -> slot 63 (lane 15, V[3])
  {
    const bool l15 = (n16 == 15);
    V[3][0] = l15 ? vp1[0] : V[3][0];
    V[3][1] = l15 ? vp1[1] : V[3][1];
    V[3][2] = l15 ? vp1[2] : V[3][2];
  }

  // ---- epilogue: kq==0 lanes hold k=0 ----
  if (kq == 0) {
    float4 o;
    float* op = &o.x;
    #pragma unroll
    for (int s = 0; s < 4; ++s) {
      float cv = -V[s][0];
      cv = fminf(fmaxf(cv, -1.f + 1e-6f), 1.f - 1e-6f);
      op[s] = acosf(cv) * (1.f / PI_F);
    }
    ((float4*)(out + b * NV))[n16] = o;
  }
}

extern "C" void kernel_launch(void* const* d_in, const int* in_sizes, int n_in,
                              void* d_out, int out_size, void* d_ws, size_t ws_size,
                              hipStream_t stream) {
  const float* z = (const float*)d_in[0];
  const float* S = (const float*)d_in[1];
  const float* w = (const float*)d_in[2];
  const float* r = (const float*)d_in[3];
  const int* max_iter = (const int*)d_in[4];
  float* Cg = (float*)d_ws;

  const int nsplit = (ws_size >= (size_t)8 * CBUF * 4) ? 8
                   : (ws_size >= (size_t)4 * CBUF * 4) ? 4 : 1;
  compute_C_kernel<<<dim3(NV, nsplit), 128, 0, stream>>>(S, w, Cg, nsplit);
  mixing_kernel<<<BATCH / 4, 256, 0, stream>>>(z, r, Cg, max_iter,
                                               (float*)d_out, nsplit);
}